// Round 1
// baseline (109.580 us; speedup 1.0000x reference)
//
#include <hip/hip_runtime.h>

#define M 64
#define FG_T 0.6f
#define BG_T 0.4f
#define PERSIST_BLOCKS 2048   // 8 blocks/CU x 256 CUs = device capacity at low VGPR

// packed column entry: (iou_bits << 32) | ~n — iou in (0,1] so the bit pattern
// is monotone; ties in iou resolve to SMALLER n (first occurrence = np argmax).
// 0 = "no entry"; fixup decodes p==0 -> anchor 0 (np argmax of an all-zero col).
//
// GT pack (written by lb_kernel, read via wave-uniform s_load in row_kernel):
//   pack[bm*2]   = {x0, y0, x1, y1}
//   pack[bm*2+1] = {area, lb, 0, 0}
//
// Candidate masks (NEW): masks[cw*B + b] = 64-bit ballot of which GTs of batch b
// strictly overlap chunk-wave cw's anchor bbox. Depends only on (cw, b) — was
// being recomputed 32x per chunk-wave inside row_kernel (24 ds_swizzle butterfly
// + ballot per wave-unit). Bit-identical to the old in-loop computation.

// -------- lb kernel: per-(b,m) column-max lower bound + GT pack + ws init ------
// Phase 1 (all B*M blocks): one wave per (b,m); lanes 0..53 each evaluate the
// EXACT iou of one of the 54 db anchors at the grid cell nearest the GT center;
// 6-step shuffle max -> guaranteed lower bound on the column max (lb > 0).
// Phase 2 (first nch*4 blocks): per chunk-wave anchor bbox + per-batch candidate
// masks, hoisted out of row_kernel.
__global__ __launch_bounds__(64) void lb_kernel(
    const float* __restrict__ gt,    // [B, M, 4] xyxy
    const float* __restrict__ db,    // [N, 4] xywh
    float4* __restrict__ pk,         // [B*M*2] GT pack
    unsigned long long* __restrict__ col,    // [B, M] — zero-initialized here
    unsigned long long* __restrict__ masks,  // [nch*4, B] candidate masks
    int N, int B, int nch)
{
#pragma clang fp contract(off)
    const int bm = blockIdx.x;       // b*M + m
    const int t  = threadIdx.x;

    // ---------------- phase 1: column lower bound + GT pack ----------------
    {
        const float4 g = ((const float4*)gt)[bm];
        const float area_g = (g.z - g.x) * (g.w - g.y);   // reference op order
        const float gcx = (g.x + g.z) * 0.5f;
        const float gcy = (g.y + g.w) * 0.5f;

        const int   fms[6] = {64, 32, 16, 8, 4, 2};
        const float stp[6] = {8.0f, 16.0f, 32.0f, 64.0f, 128.0f, 256.0f};
        const int   off[6] = {0, 36864, 46080, 48384, 48960, 49104};

        float iou = 0.0f;
        if (t < 54) {
            const int lev = t / 9, a = t - lev * 9;
            const int fx  = fms[lev];
            int x = (int)(gcx / stp[lev]); x = min(max(x, 0), fx - 1);
            int y = (int)(gcy / stp[lev]); y = min(max(y, 0), fx - 1);
            const float4 d = ((const float4*)db)[off[lev] + (y * fx + x) * 9 + a];
            float ax0 = d.x - d.z / 2.0f;
            float ay0 = d.y - d.w / 2.0f;
            float ax1 = d.x + d.z / 2.0f;
            float ay1 = d.y + d.w / 2.0f;
            float area_a = (ax1 - ax0) * (ay1 - ay0);
            float w = fmaxf(fminf(ax1, g.z) - fmaxf(ax0, g.x), 0.0f);
            float h = fmaxf(fminf(ay1, g.w) - fmaxf(ay0, g.y), 0.0f);
            float inter = w * h;
            iou = inter / ((area_a + area_g) - inter);    // exact anchor iou
        }
        #pragma unroll
        for (int o = 1; o < 64; o <<= 1) iou = fmaxf(iou, __shfl_xor(iou, o));

        if (t == 0) {
            pk[(size_t)bm * 2]     = make_float4(g.x, g.y, g.z, g.w);
            pk[(size_t)bm * 2 + 1] = make_float4(area_g, iou, 0.0f, 0.0f);
            col[bm] = 0ull;
        }
    }

    // -------- phase 2: chunk-wave bbox -> per-batch candidate masks --------
    // Same clamp (n>=N -> N-1) and same butterfly op order as row_kernel used,
    // so masks are bit-identical to what each wave-unit previously computed.
    const int nch4 = nch * 4;
    for (int cw = blockIdx.x; cw < nch4; cw += gridDim.x) {
        const int n  = cw * 64 + t;
        const int nl = (n < N) ? n : (N - 1);
        const float4 d = ((const float4*)db)[nl];
        const float ax0 = d.x - d.z / 2.0f;
        const float ay0 = d.y - d.w / 2.0f;
        const float ax1 = d.x + d.z / 2.0f;
        const float ay1 = d.y + d.w / 2.0f;

        float wx0 = ax0, wy0 = ay0, wx1 = ax1, wy1 = ay1;
        #pragma unroll
        for (int o = 1; o < 64; o <<= 1) {
            wx0 = fminf(wx0, __shfl_xor(wx0, o));
            wy0 = fminf(wy0, __shfl_xor(wy0, o));
            wx1 = fmaxf(wx1, __shfl_xor(wx1, o));
            wy1 = fmaxf(wy1, __shfl_xor(wy1, o));
        }

        for (int b = 0; b < B; ++b) {
            const float4 gl = ((const float4*)gt)[b * M + t];  // lane t = GT t
            const bool cand = (gl.x < wx1) && (gl.z > wx0) &&
                              (gl.y < wy1) && (gl.w > wy0);
            const unsigned long long mk = __ballot((int)cand);
            if (t == 0) masks[(size_t)cw * B + b] = mk;
        }
    }
}

// ------- row kernel: PERSISTENT grid-stride over (batch, chunk) units -------
// Persistent blocks keep ~8 waves/SIMD resident (TLP-saturated). Per-unit
// preamble is now a single wave-uniform s_load of the precomputed candidate
// mask (was: 24 ds_swizzle bbox butterfly + GT test + ballot, 32x-redundant
// across batches). Candidate loop is 4-wide: 4 independent IEEE div chains
// interleave to hide v_div latency, and scalar loop overhead is halved.
__global__ __launch_bounds__(256) void row_kernel(
    const float* __restrict__ gt,    // [B, M, 4] xyxy
    const int*   __restrict__ lab,   // [B, M]
    const float* __restrict__ db,    // [N, 4] xywh
    const float4* __restrict__ pk,   // [B*M*2] GT pack {xyxy},{area,lb,_,_}
    const unsigned long long* __restrict__ masks,  // [nch*4, B]
    float* __restrict__ out_loc,     // [B, N, 4]
    float* __restrict__ out_cls,     // [B, N]
    unsigned long long* __restrict__ col,  // [B, M] packed column max
    int N, int B, int nch)           // nch = ceil(N/256)
{
#pragma clang fp contract(off)
    const int tid   = threadIdx.x;
    const int total = nch * B;

    for (int u = blockIdx.x; u < total; u += gridDim.x) {
        // chunk-major: u/B = reversed chunk (heavy coarse levels first), u%B = batch
        const unsigned uu = (unsigned)u;
        const int cm    = (int)(uu / (unsigned)B);
        const int b     = (int)(uu - (unsigned)cm * (unsigned)B);
        const int chunk = nch - 1 - cm;
        const int bM    = b * M;
        const float4* __restrict__ gtb = (const float4*)gt + bM;

        const int  n     = chunk * 256 + tid;
        const bool valid = (n < N);
        const int  nl    = valid ? n : (N - 1);

        const float4 d = ((const float4*)db)[nl];
        // db_xyxy exactly as reference: c - wh/2, c + wh/2 (div by 2 is exact)
        const float ax0 = d.x - d.z / 2.0f;
        const float ay0 = d.y - d.w / 2.0f;
        const float ax1 = d.x + d.z / 2.0f;
        const float ay1 = d.y + d.w / 2.0f;
        const float area_a = (ax1 - ax0) * (ay1 - ay0);

        // precomputed candidate mask — wave-uniform index -> scalar-pipe s_load
        const int cw = __builtin_amdgcn_readfirstlane((chunk << 2) | (tid >> 6));
        unsigned long long mask = masks[(size_t)cw * B + b];

        // best=0, bi=0: all-zero row keeps bi=0 (np argmax); strict > = first max.
        float best = 0.0f;
        int   bi   = 0;

        while (mask) {
            // pop up to 4 candidates, ascending m => first-occurrence argmax
            const int m0 = __builtin_amdgcn_readfirstlane(__builtin_ctzll(mask));
            mask &= mask - 1;
            const bool h1 = (mask != 0ull);
            const int  m1 = h1 ? __builtin_amdgcn_readfirstlane(__builtin_ctzll(mask)) : m0;
            if (h1) mask &= mask - 1;
            const bool h2 = (mask != 0ull);
            const int  m2 = h2 ? __builtin_amdgcn_readfirstlane(__builtin_ctzll(mask)) : m0;
            if (h2) mask &= mask - 1;
            const bool h3 = (mask != 0ull);
            const int  m3 = h3 ? __builtin_amdgcn_readfirstlane(__builtin_ctzll(mask)) : m0;
            if (h3) mask &= mask - 1;

            // wave-uniform pack loads -> scalar pipe (s_load_dwordx4)
            const float4 pa0 = pk[(size_t)(bM + m0) * 2];
            const float4 pb0 = pk[(size_t)(bM + m0) * 2 + 1];
            const float4 pa1 = pk[(size_t)(bM + m1) * 2];
            const float4 pb1 = pk[(size_t)(bM + m1) * 2 + 1];
            const float4 pa2 = pk[(size_t)(bM + m2) * 2];
            const float4 pb2 = pk[(size_t)(bM + m2) * 2 + 1];
            const float4 pa3 = pk[(size_t)(bM + m3) * 2];
            const float4 pb3 = pk[(size_t)(bM + m3) * 2 + 1];

            // four independent intersection chains
            float i0 = fmaxf(fminf(ax1, pa0.z) - fmaxf(ax0, pa0.x), 0.0f)
                     * fmaxf(fminf(ay1, pa0.w) - fmaxf(ay0, pa0.y), 0.0f);
            float i1 = fmaxf(fminf(ax1, pa1.z) - fmaxf(ax0, pa1.x), 0.0f)
                     * fmaxf(fminf(ay1, pa1.w) - fmaxf(ay0, pa1.y), 0.0f);
            float i2 = fmaxf(fminf(ax1, pa2.z) - fmaxf(ax0, pa2.x), 0.0f)
                     * fmaxf(fminf(ay1, pa2.w) - fmaxf(ay0, pa2.y), 0.0f);
            float i3 = fmaxf(fminf(ax1, pa3.z) - fmaxf(ax0, pa3.x), 0.0f)
                     * fmaxf(fminf(ay1, pa3.w) - fmaxf(ay0, pa3.y), 0.0f);

            if (__any((i0 > 0.0f) || (i1 > 0.0f) || (i2 > 0.0f) || (i3 > 0.0f))) {
                // IEEE div: bit-exact vs np; inter==0 lanes get iou=+0.0 which
                // can neither beat best=0 (strict >) nor pass iou>=lb>0.
                // 4 independent v_div chains -> scheduler interleaves them.
                float iou0 = i0 / ((area_a + pb0.x) - i0);
                float iou1 = i1 / ((area_a + pb1.x) - i1);
                float iou2 = i2 / ((area_a + pb2.x) - i2);
                float iou3 = i3 / ((area_a + pb3.x) - i3);

                // m0 < m1 < m2 < m3; process in order => first-occurrence argmax.
                if (iou0 > best)       { best = iou0; bi = m0; }
                if (h1 && iou1 > best) { best = iou1; bi = m1; }
                if (h2 && iou2 > best) { best = iou2; bi = m2; }
                if (h3 && iou3 > best) { best = iou3; bi = m3; }

                // Column candidates: iou >= lb[m] (lb <= column max by
                // construction) — catches the argmax and all earlier ties;
                // rare, so one combined wave-uniform guard.
                const bool c0 = valid && (iou0 >= pb0.y);
                const bool c1 = h1 && valid && (iou1 >= pb1.y);
                const bool c2 = h2 && valid && (iou2 >= pb2.y);
                const bool c3 = h3 && valid && (iou3 >= pb3.y);
                if (__any(c0 || c1 || c2 || c3)) {
                    if (c0) {
                        unsigned long long p =
                            (((unsigned long long)__float_as_uint(iou0)) << 32)
                            | (unsigned int)(~(unsigned int)n);
                        atomicMax(&col[bM + m0], p);
                    }
                    if (c1) {
                        unsigned long long p =
                            (((unsigned long long)__float_as_uint(iou1)) << 32)
                            | (unsigned int)(~(unsigned int)n);
                        atomicMax(&col[bM + m1], p);
                    }
                    if (c2) {
                        unsigned long long p =
                            (((unsigned long long)__float_as_uint(iou2)) << 32)
                            | (unsigned int)(~(unsigned int)n);
                        atomicMax(&col[bM + m2], p);
                    }
                    if (c3) {
                        unsigned long long p =
                            (((unsigned long long)__float_as_uint(iou3)) << 32)
                            | (unsigned int)(~(unsigned int)n);
                        atomicMax(&col[bM + m3], p);
                    }
                }
            }
        }

        if (valid) {
            float cv;
            if (best < BG_T)      cv = 0.0f;
            else if (best < FG_T) cv = -1.0f;
            else                  cv = (float)(lab[bM + bi] + 1);

            float4 g = gtb[bi];   // divergent gather, tiny table, L1-resident
            // rcp/log epilogue: ordering decided above; absmax threshold 3.54
            // vs ~1e-5 rcp error (validated r9-r11: absmax 0.03125 unchanged).
            float bcx = (g.x + g.z) * 0.5f;
            float bcy = (g.y + g.w) * 0.5f;
            float bw  = g.z - g.x;
            float bh  = g.w - g.y;
            float rz  = __builtin_amdgcn_rcpf(d.z);
            float rw  = __builtin_amdgcn_rcpf(d.w);
            float lx = (bcx - d.x) * rz * 10.0f;
            float ly = (bcy - d.y) * rw * 10.0f;
            float lw = __logf(bw * rz) * 5.0f;
            float lh = __logf(bh * rw) * 5.0f;

            ((float4*)out_loc)[(size_t)b * N + n] = make_float4(lx, ly, lw, lh);
            out_cls[(size_t)b * N + n] = cv;
        }
    }
}

// Apply the best_p_idx override: best_t_idx[best_p[m]] = m (last write wins),
// best_t -> 2.0 so cls = lab+1 and loc re-encoded from gt[m]. Separate dispatch:
// the kernel boundary provides cross-XCD coherence for free — fusing this with
// device-scope fences cost 4.5x (r7).
__global__ void fixup_kernel(
    const float* __restrict__ gt,
    const int*   __restrict__ lab,
    const float* __restrict__ db,
    const unsigned long long* __restrict__ col,
    float* __restrict__ out_loc,
    float* __restrict__ out_cls,
    int N)
{
#pragma clang fp contract(off)
    __shared__ int s_a[M];
    const int b = blockIdx.x;
    const int m = threadIdx.x;  // 64 threads

    unsigned long long p = col[b * M + m];
    // p==0: no anchor overlapped GT m -> np argmax of all-zero column = 0.
    int a = (p == 0ull) ? 0 : (int)(~(unsigned int)(p & 0xFFFFFFFFull));
    a = min(max(a, 0), N - 1);   // defensive clamp: no-op for kernel-produced values
    s_a[m] = a;
    __syncthreads();

    // last-write-wins for duplicate anchors (np fancy assignment semantics)
    bool write = true;
    for (int mm = m + 1; mm < M; ++mm) {
        if (s_a[mm] == a) { write = false; break; }
    }
    if (write) {
        float4 d = ((const float4*)db)[a];
        float4 g = ((const float4*)gt)[b * M + m];
        float bcx = (g.x + g.z) / 2.0f;
        float bcy = (g.y + g.w) / 2.0f;
        float bw  = g.z - g.x;
        float bh  = g.w - g.y;
        float lx = ((bcx - d.x) / d.z) / 0.1f;
        float ly = ((bcy - d.y) / d.w) / 0.1f;
        float lw = __logf(bw / d.z) / 0.2f;
        float lh = __logf(bh / d.w) / 0.2f;

        ((float4*)out_loc)[(size_t)b * N + a] = make_float4(lx, ly, lw, lh);
        out_cls[(size_t)b * N + a] = (float)(lab[b * M + m] + 1);  // best_t = 2.0
    }
}

extern "C" void kernel_launch(void* const* d_in, const int* in_sizes, int n_in,
                              void* d_out, int out_size, void* d_ws, size_t ws_size,
                              hipStream_t stream) {
    const float* gt  = (const float*)d_in[0];   // gt_boxes  [B, M, 4] xyxy
    const int*   lab = (const int*)d_in[1];     // labels    [B, M]
    const float* db  = (const float*)d_in[2];   // default_boxes [N, 4] xywh

    const int B = in_sizes[1] / M;
    const int N = in_sizes[2] / 4;
    const int nch = (N + 255) / 256;

    float* out_loc = (float*)d_out;                       // [B, N, 4]
    float* out_cls = out_loc + (size_t)B * N * 4;         // [B, N]

    unsigned long long* col = (unsigned long long*)d_ws;            // [B, M] u64
    float4*             pkp = (float4*)(col + (size_t)B * M);       // [B*M*2] f32x4
    unsigned long long* msk = (unsigned long long*)(pkp + (size_t)B * M * 2); // [nch*4, B]

    const int total = nch * B;
    const int grid  = total < PERSIST_BLOCKS ? total : PERSIST_BLOCKS;

    lb_kernel<<<dim3(B * M), dim3(64), 0, stream>>>(gt, db, pkp, col, msk, N, B, nch);
    row_kernel<<<dim3(grid), dim3(256), 0, stream>>>(
        gt, lab, db, pkp, msk, out_loc, out_cls, col, N, B, nch);
    fixup_kernel<<<dim3(B), dim3(M), 0, stream>>>(gt, lab, db, col, out_loc, out_cls, N);
}

// Round 3
// 98.958 us; speedup vs baseline: 1.1073x; 1.1073x over previous
//
#include <hip/hip_runtime.h>

#define M 64
#define FG_T 0.6f
#define BG_T 0.4f
#define PERSIST_BLOCKS 2048   // 8 blocks/CU x 256 CUs = device capacity at 16 VGPR

// packed column entry: (iou_bits << 32) | ~n — iou in (0,1] so the bit pattern
// is monotone; ties in iou resolve to SMALLER n (first occurrence = np argmax).
// 0 = "no entry"; fixup decodes p==0 -> anchor 0 (np argmax of an all-zero col).
//
// GT pack (written by lb_kernel, read via wave-uniform s_load in row_kernel):
//   pack[bm*2]   = {x0, y0, x1, y1}
//   pack[bm*2+1] = {area, lb, 0, 0}

// -------- lb kernel: per-(b,m) column-max lower bound + GT pack + ws init ------
// One wave per (b,m): lanes 0..53 each evaluate the EXACT iou (same op order
// as everywhere) of one of the 54 db anchors at the grid cell nearest the GT
// center (6 levels x 9 shapes); 6-step shuffle max. Each candidate is a real
// anchor's iou -> guaranteed lower bound on the column max; the nearest L5
// (384px) anchor always intersects, so lb > 0 for every GT.
__global__ __launch_bounds__(64) void lb_kernel(
    const float* __restrict__ gt,    // [B, M, 4] xyxy
    const float* __restrict__ db,    // [N, 4] xywh
    float4* __restrict__ pk,         // [B*M*2] GT pack
    unsigned long long* __restrict__ col)  // [B, M] — zero-initialized here
{
#pragma clang fp contract(off)
    const int bm = blockIdx.x;       // b*M + m
    const int t  = threadIdx.x;

    const float4 g = ((const float4*)gt)[bm];
    const float area_g = (g.z - g.x) * (g.w - g.y);   // reference op order
    const float gcx = (g.x + g.z) * 0.5f;
    const float gcy = (g.y + g.w) * 0.5f;

    const int   fms[6] = {64, 32, 16, 8, 4, 2};
    const float stp[6] = {8.0f, 16.0f, 32.0f, 64.0f, 128.0f, 256.0f};
    const int   off[6] = {0, 36864, 46080, 48384, 48960, 49104};

    float iou = 0.0f;
    if (t < 54) {
        const int lev = t / 9, a = t - lev * 9;
        const int fx  = fms[lev];
        int x = (int)(gcx / stp[lev]); x = min(max(x, 0), fx - 1);
        int y = (int)(gcy / stp[lev]); y = min(max(y, 0), fx - 1);
        const float4 d = ((const float4*)db)[off[lev] + (y * fx + x) * 9 + a];
        float ax0 = d.x - d.z / 2.0f;
        float ay0 = d.y - d.w / 2.0f;
        float ax1 = d.x + d.z / 2.0f;
        float ay1 = d.y + d.w / 2.0f;
        float area_a = (ax1 - ax0) * (ay1 - ay0);
        float w = fmaxf(fminf(ax1, g.z) - fmaxf(ax0, g.x), 0.0f);
        float h = fmaxf(fminf(ay1, g.w) - fmaxf(ay0, g.y), 0.0f);
        float inter = w * h;
        iou = inter / ((area_a + area_g) - inter);    // exact anchor iou
    }
    #pragma unroll
    for (int o = 1; o < 64; o <<= 1) iou = fmaxf(iou, __shfl_xor(iou, o));

    if (t == 0) {
        pk[(size_t)bm * 2]     = make_float4(g.x, g.y, g.z, g.w);
        pk[(size_t)bm * 2 + 1] = make_float4(area_g, iou, 0.0f, 0.0f);
        col[bm] = 0ull;
    }
}

// ------- row kernel: PERSISTENT grid-stride over (batch, chunk) units -------
// Persistent blocks keep ~8 waves/SIMD resident (TLP-saturated); remaining
// lever is VALU issue count per candidate. GT fragments come from the pack
// via wave-uniform index (readfirstlane) -> scalar-pipe s_load_dwordx4,
// replacing 13 v_readlane VALU slots per 2-GT iteration.
__global__ __launch_bounds__(256) void row_kernel(
    const float* __restrict__ gt,    // [B, M, 4] xyxy
    const int*   __restrict__ lab,   // [B, M]
    const float* __restrict__ db,    // [N, 4] xywh
    const float4* __restrict__ pk,   // [B*M*2] GT pack {xyxy},{area,lb,_,_}
    float* __restrict__ out_loc,     // [B, N, 4]
    float* __restrict__ out_cls,     // [B, N]
    unsigned long long* __restrict__ col,  // [B, M] packed column max
    int N, int B, int nch)           // nch = ceil(N/256)
{
#pragma clang fp contract(off)
    const int tid   = threadIdx.x;
    const int lane  = tid & 63;
    const int total = nch * B;

    for (int u = blockIdx.x; u < total; u += gridDim.x) {
        // chunk-major: u/B = reversed chunk (heavy coarse levels first), u%B = batch
        const unsigned uu = (unsigned)u;
        const int cm    = (int)(uu / (unsigned)B);
        const int b     = (int)(uu - (unsigned)cm * (unsigned)B);
        const int chunk = nch - 1 - cm;
        const int bM    = b * M;
        const float4* __restrict__ gtb = (const float4*)gt + bM;

        const int  n     = chunk * 256 + tid;
        const bool valid = (n < N);
        const int  nl    = valid ? n : (N - 1);

        const float4 d = ((const float4*)db)[nl];
        // db_xyxy exactly as reference: c - wh/2, c + wh/2 (div by 2 is exact)
        const float ax0 = d.x - d.z / 2.0f;
        const float ay0 = d.y - d.w / 2.0f;
        const float ax1 = d.x + d.z / 2.0f;
        const float ay1 = d.y + d.w / 2.0f;
        const float area_a = (ax1 - ax0) * (ay1 - ay0);

        // wave bbox (union of the wave's 64 anchors)
        float wx0 = ax0, wy0 = ay0, wx1 = ax1, wy1 = ay1;
        #pragma unroll
        for (int o = 1; o < 64; o <<= 1) {
            wx0 = fminf(wx0, __shfl_xor(wx0, o));
            wy0 = fminf(wy0, __shfl_xor(wy0, o));
            wx1 = fmaxf(wx1, __shfl_xor(wx1, o));
            wy1 = fmaxf(wy1, __shfl_xor(wy1, o));
        }

        // lane l tests GT l against the wave bbox; candidate iff strict overlap
        // (touch-only => inter==0 => iou==0 => irrelevant for row argmax and
        // column candidates since lb > 0).
        const float4 gl = gtb[lane];
        const bool cand = (gl.x < wx1) && (gl.z > wx0) && (gl.y < wy1) && (gl.w > wy0);
        unsigned long long mask = __ballot((int)cand);

        // best=0, bi=0: all-zero row keeps bi=0 (np argmax); strict > = first max.
        float best = 0.0f;
        int   bi   = 0;

        while (mask) {
            const int m0 = __builtin_amdgcn_readfirstlane(__builtin_ctzll(mask));
            mask &= mask - 1;
            const bool has2 = (mask != 0ull);
            const int m1 = has2 ? __builtin_amdgcn_readfirstlane(__builtin_ctzll(mask)) : m0;
            if (has2) mask &= mask - 1;

            // wave-uniform pack loads -> scalar pipe (s_load_dwordx4)
            const float4 pa0 = pk[(size_t)(bM + m0) * 2];
            const float4 pb0 = pk[(size_t)(bM + m0) * 2 + 1];
            const float4 pa1 = pk[(size_t)(bM + m1) * 2];
            const float4 pb1 = pk[(size_t)(bM + m1) * 2 + 1];

            // two independent intersection chains (no VCC hazard here)
            float i0 = fmaxf(fminf(ax1, pa0.z) - fmaxf(ax0, pa0.x), 0.0f)
                     * fmaxf(fminf(ay1, pa0.w) - fmaxf(ay0, pa0.y), 0.0f);
            float i1 = fmaxf(fminf(ax1, pa1.z) - fmaxf(ax0, pa1.x), 0.0f)
                     * fmaxf(fminf(ay1, pa1.w) - fmaxf(ay0, pa1.y), 0.0f);

            if (__any((i0 > 0.0f) || (i1 > 0.0f))) {
                // IEEE div: bit-exact vs np; inter==0 lanes get iou=+0.0 which
                // can neither beat best=0 (strict >) nor pass iou>=lb>0.
                float iou0 = i0 / ((area_a + pb0.x) - i0);
                float iou1 = i1 / ((area_a + pb1.x) - i1);

                // m0 < m1 always; process in order => first-occurrence argmax.
                if (iou0 > best)         { best = iou0; bi = m0; }
                if (has2 && iou1 > best) { best = iou1; bi = m1; }

                // Column candidates: iou >= lb[m] (lb <= column max by
                // construction) — catches the argmax and all earlier ties;
                // rare, so one combined wave-uniform guard.
                const bool c0 = valid && (iou0 >= pb0.y);
                const bool c1 = has2 && valid && (iou1 >= pb1.y);
                if (__any(c0 || c1)) {
                    if (c0) {
                        unsigned long long p =
                            (((unsigned long long)__float_as_uint(iou0)) << 32)
                            | (unsigned int)(~(unsigned int)n);
                        atomicMax(&col[bM + m0], p);
                    }
                    if (c1) {
                        unsigned long long p =
                            (((unsigned long long)__float_as_uint(iou1)) << 32)
                            | (unsigned int)(~(unsigned int)n);
                        atomicMax(&col[bM + m1], p);
                    }
                }
            }
        }

        if (valid) {
            float cv;
            if (best < BG_T)      cv = 0.0f;
            else if (best < FG_T) cv = -1.0f;
            else                  cv = (float)(lab[bM + bi] + 1);

            float4 g = gtb[bi];   // divergent gather, tiny table, L1-resident
            // rcp/log epilogue: ordering decided above; absmax threshold 3.54
            // vs ~1e-5 rcp error (validated r9-r11: absmax 0.03125 unchanged).
            float bcx = (g.x + g.z) * 0.5f;
            float bcy = (g.y + g.w) * 0.5f;
            float bw  = g.z - g.x;
            float bh  = g.w - g.y;
            float rz  = __builtin_amdgcn_rcpf(d.z);
            float rw  = __builtin_amdgcn_rcpf(d.w);
            float lx = (bcx - d.x) * rz * 10.0f;
            float ly = (bcy - d.y) * rw * 10.0f;
            float lw = __logf(bw * rz) * 5.0f;
            float lh = __logf(bh * rw) * 5.0f;

            ((float4*)out_loc)[(size_t)b * N + n] = make_float4(lx, ly, lw, lh);
            out_cls[(size_t)b * N + n] = cv;
        }
    }
}

// Apply the best_p_idx override: best_t_idx[best_p[m]] = m (last write wins),
// best_t -> 2.0 so cls = lab+1 and loc re-encoded from gt[m]. Separate dispatch:
// the kernel boundary provides cross-XCD coherence for free — fusing this with
// device-scope fences cost 4.5x (r7).
__global__ void fixup_kernel(
    const float* __restrict__ gt,
    const int*   __restrict__ lab,
    const float* __restrict__ db,
    const unsigned long long* __restrict__ col,
    float* __restrict__ out_loc,
    float* __restrict__ out_cls,
    int N)
{
#pragma clang fp contract(off)
    __shared__ int s_a[M];
    const int b = blockIdx.x;
    const int m = threadIdx.x;  // 64 threads

    unsigned long long p = col[b * M + m];
    // p==0: no anchor overlapped GT m -> np argmax of all-zero column = 0.
    int a = (p == 0ull) ? 0 : (int)(~(unsigned int)(p & 0xFFFFFFFFull));
    a = min(max(a, 0), N - 1);   // defensive clamp: no-op for kernel-produced values
    s_a[m] = a;
    __syncthreads();

    // last-write-wins for duplicate anchors (np fancy assignment semantics)
    bool write = true;
    for (int mm = m + 1; mm < M; ++mm) {
        if (s_a[mm] == a) { write = false; break; }
    }
    if (write) {
        float4 d = ((const float4*)db)[a];
        float4 g = ((const float4*)gt)[b * M + m];
        float bcx = (g.x + g.z) / 2.0f;
        float bcy = (g.y + g.w) / 2.0f;
        float bw  = g.z - g.x;
        float bh  = g.w - g.y;
        float lx = ((bcx - d.x) / d.z) / 0.1f;
        float ly = ((bcy - d.y) / d.w) / 0.1f;
        float lw = __logf(bw / d.z) / 0.2f;
        float lh = __logf(bh / d.w) / 0.2f;

        ((float4*)out_loc)[(size_t)b * N + a] = make_float4(lx, ly, lw, lh);
        out_cls[(size_t)b * N + a] = (float)(lab[b * M + m] + 1);  // best_t = 2.0
    }
}

extern "C" void kernel_launch(void* const* d_in, const int* in_sizes, int n_in,
                              void* d_out, int out_size, void* d_ws, size_t ws_size,
                              hipStream_t stream) {
    const float* gt  = (const float*)d_in[0];   // gt_boxes  [B, M, 4] xyxy
    const int*   lab = (const int*)d_in[1];     // labels    [B, M]
    const float* db  = (const float*)d_in[2];   // default_boxes [N, 4] xywh

    const int B = in_sizes[1] / M;
    const int N = in_sizes[2] / 4;
    const int nch = (N + 255) / 256;

    float* out_loc = (float*)d_out;                       // [B, N, 4]
    float* out_cls = out_loc + (size_t)B * N * 4;         // [B, N]

    unsigned long long* col = (unsigned long long*)d_ws;          // [B, M] u64
    float4*             pkp = (float4*)(col + (size_t)B * M);     // [B*M*2] f32x4

    const int total = nch * B;
    const int grid  = total < PERSIST_BLOCKS ? total : PERSIST_BLOCKS;

    lb_kernel<<<dim3(B * M), dim3(64), 0, stream>>>(gt, db, pkp, col);
    row_kernel<<<dim3(grid), dim3(256), 0, stream>>>(
        gt, lab, db, pkp, out_loc, out_cls, col, N, B, nch);
    fixup_kernel<<<dim3(B), dim3(M), 0, stream>>>(gt, lab, db, col, out_loc, out_cls, N);
}